// Round 1
// baseline (5424.491 us; speedup 1.0000x reference)
//
#include <hip/hip_runtime.h>
#include <hip/hip_fp16.h>
#include <math.h>

// Problem constants
#define NB 2048      // batch
#define ND 1024      // dim
#define EPS 0.05f
#define NITER 100
#define SBLK 256     // sinkhorn blocks
#define RPB 8        // rows per sinkhorn block

// ---------------- prep: w = nan_to_num(diag(L)), init u/v, zero barrier+max ----------------
__global__ void prep_k(const float* __restrict__ L, float* __restrict__ w,
                       float* __restrict__ u, float* __restrict__ v,
                       unsigned* __restrict__ maxbits, int* __restrict__ barr) {
    int gtid = blockIdx.x * 256 + threadIdx.x;   // 0..2047
    if (gtid < ND) {
        float x = L[(size_t)gtid * (ND + 1)];
        if (x != x) x = 0.f;
        else if (fabsf(x) == INFINITY) x = (x > 0.f) ? 3.4028235e38f : -3.4028235e38f;
        w[gtid] = x;
    }
    u[gtid] = 1.0f / NB;
    v[gtid] = 1.0f / NB;
    if (gtid == 0) *maxbits = 0u;
    if (gtid < 512) barr[gtid] = 0;
}

// ---------------- per-row weighted squared norms ----------------
__global__ __launch_bounds__(256) void rows_k(const float* __restrict__ audio,
                                              const float* __restrict__ text,
                                              const float* __restrict__ w,
                                              float* __restrict__ aw, float* __restrict__ tw) {
    int r = blockIdx.x, tid = threadIdx.x;
    float4 wv = *(const float4*)&w[tid * 4];
    float4 a4 = *(const float4*)&audio[(size_t)r * ND + tid * 4];
    float4 t4 = *(const float4*)&text[(size_t)r * ND + tid * 4];
    float sa = a4.x * a4.x * wv.x + a4.y * a4.y * wv.y + a4.z * a4.z * wv.z + a4.w * a4.w * wv.w;
    float st = t4.x * t4.x * wv.x + t4.y * t4.y * wv.y + t4.z * t4.z * wv.z + t4.w * t4.w * wv.w;
    #pragma unroll
    for (int off = 32; off; off >>= 1) {
        sa += __shfl_down(sa, off, 64);
        st += __shfl_down(st, off, 64);
    }
    __shared__ float red[8];
    if ((tid & 63) == 0) { red[tid >> 6] = sa; red[4 + (tid >> 6)] = st; }
    __syncthreads();
    if (tid == 0) {
        aw[r] = red[0] + red[1] + red[2] + red[3];
        tw[r] = red[4] + red[5] + red[6] + red[7];
    }
}

// ---------------- f32 GEMM -> M_dist (f16, row + col major) + global max ----------------
__global__ __launch_bounds__(256) void gemm_mdist(
        const float* __restrict__ Tm, const float* __restrict__ Am,
        const float* __restrict__ w, const float* __restrict__ tw, const float* __restrict__ aw,
        __half* __restrict__ Md, __half* __restrict__ MdT,
        float* __restrict__ diagMd, unsigned* __restrict__ maxbits) {
    __shared__ float As[16][64];
    __shared__ float Bs[16][64];
    __shared__ __half Tt[64][65];
    __shared__ float wmax[4];
    const int tid = threadIdx.x;
    const int row0 = blockIdx.y * 64, col0 = blockIdx.x * 64;
    const int ty = tid >> 4, tx = tid & 15;
    const int lr = tid >> 2, lk = (tid & 3) << 2;
    float acc[4][4] = {};
    const float* tp = Tm + (size_t)(row0 + lr) * ND + lk;
    const float* ap = Am + (size_t)(col0 + lr) * ND + lk;
    for (int k0 = 0; k0 < ND; k0 += 16) {
        float4 av = *(const float4*)(tp + k0);
        float4 wv = *(const float4*)(w + k0 + lk);
        float4 bv = *(const float4*)(ap + k0);
        av.x *= wv.x; av.y *= wv.y; av.z *= wv.z; av.w *= wv.w;
        __syncthreads();
        As[lk + 0][lr] = av.x; As[lk + 1][lr] = av.y; As[lk + 2][lr] = av.z; As[lk + 3][lr] = av.w;
        Bs[lk + 0][lr] = bv.x; Bs[lk + 1][lr] = bv.y; Bs[lk + 2][lr] = bv.z; Bs[lk + 3][lr] = bv.w;
        __syncthreads();
        #pragma unroll
        for (int kk = 0; kk < 16; ++kk) {
            float4 af = *(const float4*)&As[kk][ty << 2];
            float4 bf = *(const float4*)&Bs[kk][tx << 2];
            float a[4] = {af.x, af.y, af.z, af.w};
            float b[4] = {bf.x, bf.y, bf.z, bf.w};
            #pragma unroll
            for (int m = 0; m < 4; ++m)
                #pragma unroll
                for (int n = 0; n < 4; ++n)
                    acc[m][n] = fmaf(a[m], b[n], acc[m][n]);
        }
    }
    // epilogue: md = sqrt(max(tw+aw-2*cross,0))
    const int i0 = row0 + (ty << 2), j0 = col0 + (tx << 2);
    float lmax = 0.f;
    #pragma unroll
    for (int m = 0; m < 4; ++m) {
        const float twi = tw[i0 + m];
        #pragma unroll
        for (int n = 0; n < 4; ++n) {
            float md = twi + aw[j0 + n] - 2.0f * acc[m][n];
            md = sqrtf(fmaxf(md, 0.f));
            lmax = fmaxf(lmax, md);
            __half h = __float2half(md);
            Md[(size_t)(i0 + m) * NB + (j0 + n)] = h;
            Tt[(tx << 2) + n][(ty << 2) + m] = h;
            if (i0 + m == j0 + n) diagMd[i0 + m] = md;
        }
    }
    __syncthreads();
    // transposed tile write (coalesced along ii)
    for (int e = tid; e < 4096; e += 256) {
        int jj = e >> 6, ii = e & 63;
        MdT[(size_t)(col0 + jj) * NB + (row0 + ii)] = Tt[jj][ii];
    }
    #pragma unroll
    for (int off = 32; off; off >>= 1) lmax = fmaxf(lmax, __shfl_down(lmax, off, 64));
    if ((tid & 63) == 0) wmax[tid >> 6] = lmax;
    __syncthreads();
    if (tid == 0) {
        float m2 = fmaxf(fmaxf(wmax[0], wmax[1]), fmaxf(wmax[2], wmax[3]));
        atomicMax(maxbits, __float_as_uint(m2));
    }
}

// ---------------- hierarchical device-scope grid barrier ----------------
// barr layout (ints): [0]=phase, [32]=root counter, [64+g*32]=group counters g=0..7
__device__ __forceinline__ void gsync(int* barr, int target) {
    __syncthreads();
    if (threadIdx.x == 0) {
        const int g = blockIdx.x & 7;
        int prev = __hip_atomic_fetch_add(&barr[64 + g * 32], 1, __ATOMIC_ACQ_REL, __HIP_MEMORY_SCOPE_AGENT);
        if (prev == (SBLK / 8) - 1) {
            __hip_atomic_store(&barr[64 + g * 32], 0, __ATOMIC_RELAXED, __HIP_MEMORY_SCOPE_AGENT);
            int rp = __hip_atomic_fetch_add(&barr[32], 1, __ATOMIC_ACQ_REL, __HIP_MEMORY_SCOPE_AGENT);
            if (rp == 7) {
                __hip_atomic_store(&barr[32], 0, __ATOMIC_RELAXED, __HIP_MEMORY_SCOPE_AGENT);
                __hip_atomic_store(&barr[0], target, __ATOMIC_RELEASE, __HIP_MEMORY_SCOPE_AGENT);
            }
        }
        while (__hip_atomic_load(&barr[0], __ATOMIC_ACQUIRE, __HIP_MEMORY_SCOPE_AGENT) < target) {
            __builtin_amdgcn_s_sleep(2);
        }
    }
    __syncthreads();
}

// ---------------- persistent Sinkhorn: 100 x { v = b/(K^T u); u = a/(K v) } ----------------
__global__ __launch_bounds__(256, 1) void sinkhorn_k(
        const __half* __restrict__ Md, const __half* __restrict__ MdT,
        float* __restrict__ u, float* __restrict__ v,
        const unsigned* __restrict__ maxbits, int* __restrict__ barr) {
    __shared__ float sv[NB];
    const int tid = threadIdx.x, bid = blockIdx.x;
    const int g = tid >> 5, l = tid & 31;
    const int row = (bid << 3) + g;
    const float mx = __uint_as_float(*maxbits);
    const float cc = -1.0f / (mx * EPS);     // K = exp(md * cc)
    const float ab = 1.0f / NB;
    const __half* __restrict__ rT = MdT + (size_t)row * NB;
    const __half* __restrict__ rM = Md + (size_t)row * NB;
    int phase = 0;
    union U { float4 f; __half2 h[4]; };
    for (int it = 0; it < NITER; ++it) {
        // ---- v-step: v[row] = b / sum_i exp(mdT[row][i]*cc) * u[i] ----
        for (int s = tid; s < NB; s += 256)
            sv[s] = __hip_atomic_load(&u[s], __ATOMIC_RELAXED, __HIP_MEMORY_SCOPE_AGENT);
        __syncthreads();
        float sum = 0.f;
        #pragma unroll
        for (int c8 = 0; c8 < 8; ++c8) {
            int base = (c8 << 8) + (l << 3);
            U uu; uu.f = *(const float4*)(rT + base);
            #pragma unroll
            for (int q = 0; q < 4; ++q) {
                float2 f = __half22float2(uu.h[q]);
                sum = fmaf(__expf(f.x * cc), sv[base + (q << 1)], sum);
                sum = fmaf(__expf(f.y * cc), sv[base + (q << 1) + 1], sum);
            }
        }
        #pragma unroll
        for (int off = 16; off; off >>= 1) sum += __shfl_down(sum, off, 32);
        if (l == 0) __hip_atomic_store(&v[row], ab / sum, __ATOMIC_RELEASE, __HIP_MEMORY_SCOPE_AGENT);
        gsync(barr, ++phase);
        // ---- u-step: u[row] = a / sum_j exp(md[row][j]*cc) * v[j] ----
        for (int s = tid; s < NB; s += 256)
            sv[s] = __hip_atomic_load(&v[s], __ATOMIC_RELAXED, __HIP_MEMORY_SCOPE_AGENT);
        __syncthreads();
        sum = 0.f;
        #pragma unroll
        for (int c8 = 0; c8 < 8; ++c8) {
            int base = (c8 << 8) + (l << 3);
            U uu; uu.f = *(const float4*)(rM + base);
            #pragma unroll
            for (int q = 0; q < 4; ++q) {
                float2 f = __half22float2(uu.h[q]);
                sum = fmaf(__expf(f.x * cc), sv[base + (q << 1)], sum);
                sum = fmaf(__expf(f.y * cc), sv[base + (q << 1) + 1], sum);
            }
        }
        #pragma unroll
        for (int off = 16; off; off >>= 1) sum += __shfl_down(sum, off, 32);
        if (l == 0) __hip_atomic_store(&u[row], ab / sum, __ATOMIC_RELEASE, __HIP_MEMORY_SCOPE_AGENT);
        gsync(barr, ++phase);
    }
}

// ---------------- loss: -(1/B) * sum_i [log u_i + log v_i + log K_ii] ----------------
__global__ void loss_k(const float* __restrict__ u, const float* __restrict__ v,
                       const float* __restrict__ diagMd, const unsigned* __restrict__ maxbits,
                       float* __restrict__ out) {
    int tid = threadIdx.x;
    float mx = __uint_as_float(*maxbits);
    float cc = 1.0f / (mx * EPS);
    double s = 0.0;
    for (int i = tid; i < NB; i += 256)
        s += (double)(logf(u[i]) + logf(v[i]) - diagMd[i] * cc);
    #pragma unroll
    for (int off = 32; off; off >>= 1) s += __shfl_down(s, off, 64);
    __shared__ double red[4];
    if ((tid & 63) == 0) red[tid >> 6] = s;
    __syncthreads();
    if (tid == 0) out[0] = (float)(-(red[0] + red[1] + red[2] + red[3]) / (double)NB);
}

// ---------------- launch ----------------
extern "C" void kernel_launch(void* const* d_in, const int* in_sizes, int n_in,
                              void* d_out, int out_size, void* d_ws, size_t ws_size,
                              hipStream_t stream) {
    const float* audio = (const float*)d_in[0];
    const float* text  = (const float*)d_in[1];
    const float* L     = (const float*)d_in[2];
    char* ws = (char*)d_ws;
    float*    w       = (float*)(ws + 0);
    float*    aw      = (float*)(ws + 4096);
    float*    tw      = (float*)(ws + 12288);
    float*    u       = (float*)(ws + 20480);
    float*    v       = (float*)(ws + 28672);
    float*    diagMd  = (float*)(ws + 36864);
    unsigned* maxbits = (unsigned*)(ws + 45056);
    int*      barr    = (int*)(ws + 45312);
    __half*   Md      = (__half*)(ws + 65536);
    __half*   MdT     = (__half*)(ws + 65536 + (size_t)NB * NB * 2);

    prep_k<<<8, 256, 0, stream>>>(L, w, u, v, maxbits, barr);
    rows_k<<<NB, 256, 0, stream>>>(audio, text, w, aw, tw);
    gemm_mdist<<<dim3(32, 32), 256, 0, stream>>>(text, audio, w, tw, aw, Md, MdT, diagMd, maxbits);
    sinkhorn_k<<<SBLK, 256, 0, stream>>>(Md, MdT, u, v, maxbits, barr);
    loss_k<<<1, 256, 0, stream>>>(u, v, diagMd, maxbits, (float*)d_out);
}

// Round 2
// 1063.980 us; speedup vs baseline: 5.0983x; 5.0983x over previous
//
#include <hip/hip_runtime.h>
#include <hip/hip_fp16.h>
#include <math.h>

// Problem constants
#define NB 2048      // batch
#define ND 1024      // dim
#define EPS 0.05f
#define NITER 100
#define SBLK 128     // sinkhorn blocks (<=256 CUs, co-resident at 1 block/CU)
#define RPB 16       // rows per sinkhorn block (NB/SBLK)
#define KSCALE 16384.0f          // 2^14 — pulls f16 K into normal range
#define LOG_KSCALE 9.704060527839234  // log(2^14)

typedef float f32x4 __attribute__((ext_vector_type(4)));
union Uh { f32x4 f; __half2 h[4]; };

// ---------------- prep: w = nan_to_num(diag(L)), init u/v, zero barrier+max ----------------
__global__ void prep_k(const float* __restrict__ L, float* __restrict__ w,
                       float* __restrict__ u, float* __restrict__ v,
                       unsigned* __restrict__ maxbits, unsigned* __restrict__ barr) {
    int gtid = blockIdx.x * 256 + threadIdx.x;   // 0..2047
    if (gtid < ND) {
        float x = L[(size_t)gtid * (ND + 1)];
        if (x != x) x = 0.f;
        else if (fabsf(x) == INFINITY) x = (x > 0.f) ? 3.4028235e38f : -3.4028235e38f;
        w[gtid] = x;
    }
    u[gtid] = 1.0f / NB;
    v[gtid] = 1.0f / NB;
    if (gtid == 0) *maxbits = 0u;
    if (gtid < 512) barr[gtid] = 0u;
}

// ---------------- per-row weighted squared norms ----------------
__global__ __launch_bounds__(256) void rows_k(const float* __restrict__ audio,
                                              const float* __restrict__ text,
                                              const float* __restrict__ w,
                                              float* __restrict__ aw, float* __restrict__ tw) {
    int r = blockIdx.x, tid = threadIdx.x;
    float4 wv = *(const float4*)&w[tid * 4];
    float4 a4 = *(const float4*)&audio[(size_t)r * ND + tid * 4];
    float4 t4 = *(const float4*)&text[(size_t)r * ND + tid * 4];
    float sa = a4.x * a4.x * wv.x + a4.y * a4.y * wv.y + a4.z * a4.z * wv.z + a4.w * a4.w * wv.w;
    float st = t4.x * t4.x * wv.x + t4.y * t4.y * wv.y + t4.z * t4.z * wv.z + t4.w * t4.w * wv.w;
    #pragma unroll
    for (int off = 32; off; off >>= 1) {
        sa += __shfl_down(sa, off, 64);
        st += __shfl_down(st, off, 64);
    }
    __shared__ float red[8];
    if ((tid & 63) == 0) { red[tid >> 6] = sa; red[4 + (tid >> 6)] = st; }
    __syncthreads();
    if (tid == 0) {
        aw[r] = red[0] + red[1] + red[2] + red[3];
        tw[r] = red[4] + red[5] + red[6] + red[7];
    }
}

// ---------------- f32 GEMM -> M_dist (f16, row + col major) + global max ----------------
__global__ __launch_bounds__(256) void gemm_mdist(
        const float* __restrict__ Tm, const float* __restrict__ Am,
        const float* __restrict__ w, const float* __restrict__ tw, const float* __restrict__ aw,
        __half* __restrict__ Md, __half* __restrict__ MdT,
        float* __restrict__ diagMd, unsigned* __restrict__ maxbits) {
    __shared__ float As[16][64];
    __shared__ float Bs[16][64];
    __shared__ __half Tt[64][65];
    __shared__ float wmax[4];
    const int tid = threadIdx.x;
    const int row0 = blockIdx.y * 64, col0 = blockIdx.x * 64;
    const int ty = tid >> 4, tx = tid & 15;
    const int lr = tid >> 2, lk = (tid & 3) << 2;
    float acc[4][4] = {};
    const float* tp = Tm + (size_t)(row0 + lr) * ND + lk;
    const float* ap = Am + (size_t)(col0 + lr) * ND + lk;
    for (int k0 = 0; k0 < ND; k0 += 16) {
        float4 av = *(const float4*)(tp + k0);
        float4 wv = *(const float4*)(w + k0 + lk);
        float4 bv = *(const float4*)(ap + k0);
        av.x *= wv.x; av.y *= wv.y; av.z *= wv.z; av.w *= wv.w;
        __syncthreads();
        As[lk + 0][lr] = av.x; As[lk + 1][lr] = av.y; As[lk + 2][lr] = av.z; As[lk + 3][lr] = av.w;
        Bs[lk + 0][lr] = bv.x; Bs[lk + 1][lr] = bv.y; Bs[lk + 2][lr] = bv.z; Bs[lk + 3][lr] = bv.w;
        __syncthreads();
        #pragma unroll
        for (int kk = 0; kk < 16; ++kk) {
            float4 af = *(const float4*)&As[kk][ty << 2];
            float4 bf = *(const float4*)&Bs[kk][tx << 2];
            float a[4] = {af.x, af.y, af.z, af.w};
            float b[4] = {bf.x, bf.y, bf.z, bf.w};
            #pragma unroll
            for (int m = 0; m < 4; ++m)
                #pragma unroll
                for (int n = 0; n < 4; ++n)
                    acc[m][n] = fmaf(a[m], b[n], acc[m][n]);
        }
    }
    // epilogue: md = sqrt(max(tw+aw-2*cross,0))
    const int i0 = row0 + (ty << 2), j0 = col0 + (tx << 2);
    float lmax = 0.f;
    #pragma unroll
    for (int m = 0; m < 4; ++m) {
        const float twi = tw[i0 + m];
        #pragma unroll
        for (int n = 0; n < 4; ++n) {
            float md = twi + aw[j0 + n] - 2.0f * acc[m][n];
            md = sqrtf(fmaxf(md, 0.f));
            lmax = fmaxf(lmax, md);
            __half h = __float2half(md);
            Md[(size_t)(i0 + m) * NB + (j0 + n)] = h;
            Tt[(tx << 2) + n][(ty << 2) + m] = h;
            if (i0 + m == j0 + n) diagMd[i0 + m] = md;
        }
    }
    __syncthreads();
    // transposed tile write (coalesced along ii)
    for (int e = tid; e < 4096; e += 256) {
        int jj = e >> 6, ii = e & 63;
        MdT[(size_t)(col0 + jj) * NB + (row0 + ii)] = Tt[jj][ii];
    }
    #pragma unroll
    for (int off = 32; off; off >>= 1) lmax = fmaxf(lmax, __shfl_down(lmax, off, 64));
    if ((tid & 63) == 0) wmax[tid >> 6] = lmax;
    __syncthreads();
    if (tid == 0) {
        float m2 = fmaxf(fmaxf(wmax[0], wmax[1]), fmaxf(wmax[2], wmax[3]));
        atomicMax(maxbits, __float_as_uint(m2));
    }
}

// ---------------- convert M_dist -> K' = exp(-md/(mx*eps)) * 2^14, in place (both majors) ----------------
__global__ __launch_bounds__(256) void expconv_k(__half* __restrict__ Kall,
                                                 const unsigned* __restrict__ maxbits) {
    const float mx = __uint_as_float(*maxbits);
    const float cc = -1.0f / (mx * EPS);
    size_t idx = ((size_t)blockIdx.x * 256 + threadIdx.x) << 3;   // 8 halfs per thread
    Uh uu; uu.f = *(const f32x4*)(Kall + idx);
    #pragma unroll
    for (int q = 0; q < 4; ++q) {
        float2 f = __half22float2(uu.h[q]);
        f.x = __expf(f.x * cc) * KSCALE;
        f.y = __expf(f.y * cc) * KSCALE;
        uu.h[q] = __floats2half2_rn(f.x, f.y);
    }
    *(f32x4*)(Kall + idx) = uu.f;
}

// ---------------- LLC-coherent 32B staged load (bypass L1/L2, no cache maintenance) ----------------
__device__ __forceinline__ void stage(const float* __restrict__ src, float* sv, int tid) {
    const float* p0 = src + (tid << 3);
    f32x4 r0, r1;
    asm volatile("global_load_dwordx4 %0, %2, off sc0 sc1\n\t"
                 "global_load_dwordx4 %1, %3, off sc0 sc1\n\t"
                 "s_waitcnt vmcnt(0)"
                 : "=&v"(r0), "=&v"(r1) : "v"(p0), "v"(p0 + 4) : "memory");
    // padded LDS layout: logical i -> i + (i/8)*4  (conflict-free b128 reads)
    *(f32x4*)&sv[tid * 12] = r0;
    *(f32x4*)&sv[tid * 12 + 4] = r1;
}

// ---------------- grid barrier: RELAXED atomics only (no buffer_inv / wbl2), monotonic counters ----------------
// barr: [0]=phase flag, [32]=root counter, [64+g*32]=group counters (g=0..7)
__device__ __forceinline__ void gsync(unsigned* barr, unsigned target) {
    __syncthreads();   // drains each wave's vmcnt before any signaling
    if (threadIdx.x == 0) {
        asm volatile("s_waitcnt vmcnt(0)" ::: "memory");
        const int g = blockIdx.x & 7;
        unsigned prev = __hip_atomic_fetch_add(&barr[64 + g * 32], 1u,
                                               __ATOMIC_RELAXED, __HIP_MEMORY_SCOPE_AGENT);
        if (prev == target * (SBLK / 8) - 1u) {          // last of group for this phase
            unsigned rp = __hip_atomic_fetch_add(&barr[32], 1u,
                                                 __ATOMIC_RELAXED, __HIP_MEMORY_SCOPE_AGENT);
            if (rp == target * 8u - 1u)                  // last group
                __hip_atomic_store(&barr[0], target, __ATOMIC_RELAXED, __HIP_MEMORY_SCOPE_AGENT);
        }
        while (__hip_atomic_load(&barr[0], __ATOMIC_RELAXED, __HIP_MEMORY_SCOPE_AGENT) < target)
            __builtin_amdgcn_s_sleep(2);
    }
    __syncthreads();
}

// ---------------- one half-step: xout[row] = ab / sum_j K[row][j] * sv[j], 4 rows per wave ----------------
__device__ __forceinline__ void half_step(const __half* __restrict__ Kmat,
                                          float* __restrict__ xout,
                                          const float* sv, int row0, float ab, int l) {
    float acc[4] = {0.f, 0.f, 0.f, 0.f};
    const __half* kb = Kmat + (size_t)row0 * NB;
    #pragma unroll
    for (int c = 0; c < 4; ++c) {
        const int col = (c << 9) + (l << 3);           // lane covers 4 chunks of 8 cols
        const int phys = col + ((col >> 3) << 2);      // padded LDS index
        f32x4 s0 = *(const f32x4*)&sv[phys];
        f32x4 s1 = *(const f32x4*)&sv[phys + 4];
        #pragma unroll
        for (int r = 0; r < 4; ++r) {
            Uh uu; uu.f = *(const f32x4*)(kb + (size_t)r * NB + col);
            float2 f0 = __half22float2(uu.h[0]);
            float2 f1 = __half22float2(uu.h[1]);
            float2 f2 = __half22float2(uu.h[2]);
            float2 f3 = __half22float2(uu.h[3]);
            acc[r] = fmaf(f0.x, s0.x, acc[r]);
            acc[r] = fmaf(f0.y, s0.y, acc[r]);
            acc[r] = fmaf(f1.x, s0.z, acc[r]);
            acc[r] = fmaf(f1.y, s0.w, acc[r]);
            acc[r] = fmaf(f2.x, s1.x, acc[r]);
            acc[r] = fmaf(f2.y, s1.y, acc[r]);
            acc[r] = fmaf(f3.x, s1.z, acc[r]);
            acc[r] = fmaf(f3.y, s1.w, acc[r]);
        }
    }
    #pragma unroll
    for (int r = 0; r < 4; ++r) {
        float s = acc[r];
        #pragma unroll
        for (int off = 32; off; off >>= 1) s += __shfl_down(s, off, 64);
        if (l == 0)
            __hip_atomic_store(&xout[row0 + r], ab / s, __ATOMIC_RELAXED, __HIP_MEMORY_SCOPE_AGENT);
    }
}

// ---------------- persistent Sinkhorn: 100 x { v = b/(K^T u); u = a/(K v) } ----------------
__global__ __launch_bounds__(256, 1) void sinkhorn_k(
        const __half* __restrict__ Kr, const __half* __restrict__ Kc,
        float* __restrict__ u, float* __restrict__ v,
        unsigned* __restrict__ barr) {
    __shared__ __align__(16) float sv[3072];   // 2048 floats, padded (i + i/8*4)
    const int tid = threadIdx.x, bid = blockIdx.x;
    const int w = tid >> 6, l = tid & 63;
    const int row0 = (bid << 4) + (w << 2);    // 16 rows/block, 4 rows/wave
    const float ab = 1.0f / NB;
    unsigned phase = 0;
    for (int it = 0; it < NITER; ++it) {
        stage(u, sv, tid);
        __syncthreads();
        half_step(Kc, v, sv, row0, ab, l);     // v-step (rows of K^T)
        gsync(barr, ++phase);
        stage(v, sv, tid);
        __syncthreads();
        half_step(Kr, u, sv, row0, ab, l);     // u-step (rows of K)
        gsync(barr, ++phase);
    }
}

// ---------------- loss: -(1/B) * sum_i [log u_i + log v_i + log K_ii] - log(2^14) ----------------
__global__ void loss_k(const float* __restrict__ u, const float* __restrict__ v,
                       const float* __restrict__ diagMd, const unsigned* __restrict__ maxbits,
                       float* __restrict__ out) {
    int tid = threadIdx.x;
    float mx = __uint_as_float(*maxbits);
    float cc = 1.0f / (mx * EPS);
    double s = 0.0;
    for (int i = tid; i < NB; i += 256)
        s += (double)(logf(u[i]) + logf(v[i]) - diagMd[i] * cc);
    #pragma unroll
    for (int off = 32; off; off >>= 1) s += __shfl_down(s, off, 64);
    __shared__ double red[4];
    if ((tid & 63) == 0) red[tid >> 6] = s;
    __syncthreads();
    if (tid == 0)
        out[0] = (float)(-(red[0] + red[1] + red[2] + red[3]) / (double)NB - LOG_KSCALE);
}

// ---------------- launch ----------------
extern "C" void kernel_launch(void* const* d_in, const int* in_sizes, int n_in,
                              void* d_out, int out_size, void* d_ws, size_t ws_size,
                              hipStream_t stream) {
    const float* audio = (const float*)d_in[0];
    const float* text  = (const float*)d_in[1];
    const float* L     = (const float*)d_in[2];
    char* ws = (char*)d_ws;
    float*    w       = (float*)(ws + 0);
    float*    aw      = (float*)(ws + 4096);
    float*    tw      = (float*)(ws + 12288);
    float*    u       = (float*)(ws + 20480);
    float*    v       = (float*)(ws + 28672);
    float*    diagMd  = (float*)(ws + 36864);
    unsigned* maxbits = (unsigned*)(ws + 45056);
    unsigned* barr    = (unsigned*)(ws + 45312);
    __half*   Md      = (__half*)(ws + 65536);                          // becomes Kr
    __half*   MdT     = (__half*)(ws + 65536 + (size_t)NB * NB * 2);    // becomes Kc

    prep_k<<<8, 256, 0, stream>>>(L, w, u, v, maxbits, barr);
    rows_k<<<NB, 256, 0, stream>>>(audio, text, w, aw, tw);
    gemm_mdist<<<dim3(32, 32), 256, 0, stream>>>(text, audio, w, tw, aw, Md, MdT, diagMd, maxbits);
    expconv_k<<<4096, 256, 0, stream>>>(Md, maxbits);   // Md & MdT are contiguous: 2*NB*NB halfs
    sinkhorn_k<<<SBLK, 256, 0, stream>>>(Md, MdT, u, v, barr);
    loss_k<<<1, 256, 0, stream>>>(u, v, diagMd, maxbits, (float*)d_out);
}